// Round 1
// baseline (345.103 us; speedup 1.0000x reference)
//
#include <hip/hip_runtime.h>
#include <cmath>

// Problem constants
#define BATCH 8192

__device__ __forceinline__ float siluf(float x){ return x / (1.f + expf(-x)); }

// C[m,n] = sum_k A[m,k] * Wrow[n,k]  (+ epilogue)
// A: M x K row-major.  W: N x K row-major (W2 used for EPI==2 rows >= nsplit).
// EPI 0: optional bias, plain store to O0 (row stride N)
// EPI 1: n<nsplit: silu(v*conv_w[n,3]+conv_b[n]) -> O0 (stride nsplit); else raw -> O1
// EPI 2: n<nsplit: tanh(v+e0[n]) -> O0 (stride nsplit); else clip(v+e1[n-ns],-5,2) -> O1
template<int TM, int TN, int TK, int RM, int RN, int EPI>
__global__ __launch_bounds__(256) void gemm_k(
    const float* __restrict__ A, const float* __restrict__ W,
    const float* __restrict__ W2, int nsplit,
    const float* __restrict__ bias,
    const float* __restrict__ e0, const float* __restrict__ e1,
    float* __restrict__ O0, float* __restrict__ O1,
    int M, int N, int K)
{
    static_assert(TM*TN == 256*RM*RN, "tile/micro mismatch");
    constexpr int PAD = 4;
    __shared__ float As[TK][TM+PAD];
    __shared__ float Ws[TK][TN+PAD];
    const int tid = threadIdx.x;
    const int m0 = blockIdx.x * TM;
    const int n0 = blockIdx.y * TN;
    constexpr int TNR = TN / RN;
    const int tm = tid / TNR;
    const int tn = tid % TNR;

    float acc[RM][RN];
#pragma unroll
    for (int i=0;i<RM;i++)
#pragma unroll
      for (int j=0;j<RN;j++) acc[i][j]=0.f;

    constexpr int K4 = TK/4;
    constexpr int AV = TM*K4/256;  // float4 loads per thread for A tile
    constexpr int WV = TN*K4/256;

    for (int k0=0;k0<K;k0+=TK){
#pragma unroll
        for (int p=0;p<AV;p++){
            const int f = tid + p*256;
            const int kf = f % K4, mm = f / K4;
            const float4 v = *reinterpret_cast<const float4*>(A + (size_t)(m0+mm)*K + k0 + kf*4);
            As[kf*4+0][mm]=v.x; As[kf*4+1][mm]=v.y; As[kf*4+2][mm]=v.z; As[kf*4+3][mm]=v.w;
        }
#pragma unroll
        for (int p=0;p<WV;p++){
            const int f = tid + p*256;
            const int kf = f % K4, nn = f / K4;
            const int ng = n0 + nn;
            float4 v = make_float4(0.f,0.f,0.f,0.f);
            if (ng < N){
                const float* src = (EPI==2 && ng >= nsplit) ? (W2 + (size_t)(ng-nsplit)*K)
                                                            : (W  + (size_t)ng*K);
                v = *reinterpret_cast<const float4*>(src + k0 + kf*4);
            }
            Ws[kf*4+0][nn]=v.x; Ws[kf*4+1][nn]=v.y; Ws[kf*4+2][nn]=v.z; Ws[kf*4+3][nn]=v.w;
        }
        __syncthreads();
#pragma unroll
        for (int k=0;k<TK;k++){
            float a[RM], b[RN];
#pragma unroll
            for (int i=0;i<RM;i+=4){
                const float4 v = *reinterpret_cast<const float4*>(&As[k][tm*RM+i]);
                a[i]=v.x;a[i+1]=v.y;a[i+2]=v.z;a[i+3]=v.w;
            }
#pragma unroll
            for (int j=0;j<RN;j+=4){
                const float4 v = *reinterpret_cast<const float4*>(&Ws[k][tn*RN+j]);
                b[j]=v.x;b[j+1]=v.y;b[j+2]=v.z;b[j+3]=v.w;
            }
#pragma unroll
            for (int i=0;i<RM;i++)
#pragma unroll
                for (int j=0;j<RN;j++)
                    acc[i][j] = fmaf(a[i], b[j], acc[i][j]);
        }
        __syncthreads();
    }

    const int mb = m0 + tm*RM;
    const int nb = n0 + tn*RN;
#pragma unroll
    for (int i=0;i<RM;i++){
        const size_t m = (size_t)(mb + i);
#pragma unroll
        for (int j=0;j<RN;j+=4){
            const int n = nb + j;
            if (n >= N) continue;   // N=48 tile guard
            float4 v = make_float4(acc[i][j],acc[i][j+1],acc[i][j+2],acc[i][j+3]);
            if (EPI==0){
                if (bias){ v.x+=bias[n]; v.y+=bias[n+1]; v.z+=bias[n+2]; v.w+=bias[n+3]; }
                *reinterpret_cast<float4*>(O0 + m*N + n) = v;
            } else if (EPI==1){
                if (n < nsplit){
                    v.x = siluf(fmaf(v.x, e0[(n+0)*4+3], e1[n+0]));
                    v.y = siluf(fmaf(v.y, e0[(n+1)*4+3], e1[n+1]));
                    v.z = siluf(fmaf(v.z, e0[(n+2)*4+3], e1[n+2]));
                    v.w = siluf(fmaf(v.w, e0[(n+3)*4+3], e1[n+3]));
                    *reinterpret_cast<float4*>(O0 + m*(size_t)nsplit + n) = v;
                } else {
                    *reinterpret_cast<float4*>(O1 + m*(size_t)nsplit + (n-nsplit)) = v;
                }
            } else {
                if (n < nsplit){
                    v.x = tanhf(v.x + e0[n+0]);
                    v.y = tanhf(v.y + e0[n+1]);
                    v.z = tanhf(v.z + e0[n+2]);
                    v.w = tanhf(v.w + e0[n+3]);
                    *reinterpret_cast<float4*>(O0 + m*(size_t)nsplit + n) = v;
                } else {
                    const int nn = n - nsplit;
                    v.x = fminf(fmaxf(v.x + e1[nn+0], -5.f), 2.f);
                    v.y = fminf(fmaxf(v.y + e1[nn+1], -5.f), 2.f);
                    v.z = fminf(fmaxf(v.z + e1[nn+2], -5.f), 2.f);
                    v.w = fminf(fmaxf(v.w + e1[nn+3], -5.f), 2.f);
                    *reinterpret_cast<float4*>(O1 + m*(size_t)nsplit + nn) = v;
                }
            }
        }
    }
}

// SSM elementwise: y = u * (softplus(dt . dtw[d] + dtb[d]) * (Bm.Cm) + Dskip[d]) * silu(z)
// One block per (b, half-of-d). x_dbl row staged in LDS. Writes y in place over U.
__global__ __launch_bounds__(256) void ssm_ew(
    const float* __restrict__ xdbl,   // (B,48): dt[0:16] Bm[16:32] Cm[32:48]
    const float* __restrict__ dtw,    // (512,16)
    const float* __restrict__ dtb,    // (512)
    const float* __restrict__ dskip,  // (512)
    const float* __restrict__ Z,      // (B,512)
    float* __restrict__ U)            // (B,512) in/out
{
    __shared__ float sxd[48];
    const int b = blockIdx.x;
    const int tid = threadIdx.x;
    const int d = blockIdx.y*256 + tid;
    if (tid < 48) sxd[tid] = xdbl[(size_t)b*48 + tid];
    __syncthreads();
    float BC = 0.f;
#pragma unroll
    for (int n=0;n<16;n++) BC = fmaf(sxd[16+n], sxd[32+n], BC);
    float dtv = dtb[d];
#pragma unroll
    for (int r=0;r<16;r++) dtv = fmaf(sxd[r], dtw[d*16+r], dtv);
    const float delta = (dtv > 20.f) ? dtv : log1pf(expf(dtv));
    const size_t off = (size_t)b*512 + d;
    const float u = U[off];
    const float z = Z[off];
    float y = u * fmaf(delta, BC, dskip[d]);
    y *= z / (1.f + expf(-z));
    U[off] = y;
}

extern "C" void kernel_launch(void* const* d_in, const int* in_sizes, int n_in,
                              void* d_out, int out_size, void* d_ws, size_t ws_size,
                              hipStream_t stream) {
    (void)in_sizes; (void)n_in; (void)out_size; (void)ws_size;
    const float* percep  = (const float*)d_in[0];   // (8192,512)
    const float* W_in    = (const float*)d_in[1];   // (256,512)
    const float* b_in    = (const float*)d_in[2];   // (256)
    const float* mu_w    = (const float*)d_in[3];   // (64,256)
    const float* mu_b    = (const float*)d_in[4];   // (64)
    const float* ls_w    = (const float*)d_in[5];   // (64,256)
    const float* ls_b    = (const float*)d_in[6];   // (64)
    const float* in_proj = (const float*)d_in[7];   // (1024,256)
    const float* conv_w  = (const float*)d_in[8];   // (512,4)
    const float* conv_b  = (const float*)d_in[9];   // (512)
    const float* x_proj  = (const float*)d_in[10];  // (48,512)
    const float* dt_w    = (const float*)d_in[11];  // (512,16)
    const float* dt_b    = (const float*)d_in[12];  // (512)
    // d_in[13] = A_log: unused (h0 = 0 kills the exp(dA) term at L=1)
    const float* Dskip   = (const float*)d_in[14];  // (512)
    const float* out_proj= (const float*)d_in[15];  // (256,512)

    float* ws = (float*)d_ws;
    float* x_ws  = ws;                       // 8192*256  = 2,097,152 floats
    float* u_ws  = ws + 2097152;             // 8192*512  = 4,194,304
    float* z_ws  = ws + 6291456;             // 8192*512  = 4,194,304
    float* xd_ws = ws + 10485760;            // 8192*48   =   393,216
    float* h_ws  = ws;                       // reuse x slot (x dead after GEMM2)

    float* mu_o = (float*)d_out;
    float* ls_o = (float*)d_out + (size_t)BATCH*64;

    dim3 blk(256);
    // 1) x = p @ W_in.T + b_in     (8192x512 -> 256)
    gemm_k<128,64,16,8,4,0><<<dim3(64,4),blk,0,stream>>>(
        percep, W_in, nullptr, 0, b_in, nullptr, nullptr, x_ws, nullptr, BATCH, 256, 512);
    // 2) xz = x @ in_proj.T; u-half: silu(conv); z-half raw   (K=256, N=1024)
    gemm_k<128,128,16,8,8,1><<<dim3(64,8),blk,0,stream>>>(
        x_ws, in_proj, nullptr, 512, nullptr, conv_w, conv_b, u_ws, z_ws, BATCH, 1024, 256);
    // 3) x_dbl = u @ x_proj.T      (K=512, N=48)
    gemm_k<64,64,16,4,4,0><<<dim3(128,1),blk,0,stream>>>(
        u_ws, x_proj, nullptr, 0, nullptr, nullptr, nullptr, xd_ws, nullptr, BATCH, 48, 512);
    // 4) y = u*(softplus(dt.dtw+dtb)*(B.C)+Dskip)*silu(z)  -> overwrite u
    ssm_ew<<<dim3(BATCH,2),blk,0,stream>>>(xd_ws, dt_w, dt_b, Dskip, z_ws, u_ws);
    // 5) h = y @ out_proj.T        (K=512, N=256)
    gemm_k<128,64,16,8,4,0><<<dim3(64,4),blk,0,stream>>>(
        u_ws, out_proj, nullptr, 0, nullptr, nullptr, nullptr, h_ws, nullptr, BATCH, 256, 512);
    // 6) mu = tanh(h@mu_w.T+mu_b); ls = clip(h@ls_w.T+ls_b,-5,2)  (K=256, N=128)
    gemm_k<64,64,16,4,4,2><<<dim3(128,2),blk,0,stream>>>(
        h_ws, mu_w, ls_w, 64, nullptr, mu_b, ls_b, mu_o, ls_o, BATCH, 128, 256);
}

// Round 2
// 270.670 us; speedup vs baseline: 1.2750x; 1.2750x over previous
//
#include <hip/hip_runtime.h>
#include <hip/hip_fp16.h>
#include <cmath>

#define BATCH 8192

typedef short bf16x8 __attribute__((ext_vector_type(8)));
typedef float f32x4 __attribute__((ext_vector_type(4)));

__device__ __forceinline__ float bf2f(unsigned short s){
    return __uint_as_float(((unsigned)s) << 16);
}

// fp32 -> bf16 hi (RNE) + bf16 lo (RNE of residual)
__device__ __forceinline__ void split2(float x, unsigned short& h, unsigned short& l){
    unsigned u = __float_as_uint(x);
    unsigned hr = u + 0x7fffu + ((u >> 16) & 1u);
    unsigned short hs = (unsigned short)(hr >> 16);
    float hf = __uint_as_float(((unsigned)hs) << 16);
    float d = x - hf;
    unsigned v = __float_as_uint(d);
    unsigned short ls = (unsigned short)((v + 0x7fffu + ((v >> 16) & 1u)) >> 16);
    h = hs; l = ls;
}

// ---------------------------------------------------------------------------
// fp32 vector GEMM: C[m,n] = sum_k A[m,k] * B[n,k]  (BL=0, B is N x K)
//                   or sum_k A[m,k] * B[k,n]        (BL=1, B is K x N)
// APAIR: A given as two bf16 bit-planes (A=hi, Alo=lo), reconstructed hi+lo.
// EPI 0: (+bias[n] if bias) -> O0 (row stride N)
// EPI 3: row-scale (m<nsplit: *scale4[m*4+3]) then split to bf16 pair ->
//        ((ushort*)O0)[m*N+n] = hi, ((ushort*)O1)[...] = lo
// ---------------------------------------------------------------------------
template<int TM,int TN,int TK,int RM,int RN,int EPI,int BL,int APAIR>
__global__ __launch_bounds__(256) void gemm_k(
    const float* __restrict__ A, const float* __restrict__ Alo,
    const float* __restrict__ W,
    const float* __restrict__ bias, const float* __restrict__ scale4,
    float* __restrict__ O0, float* __restrict__ O1,
    int nsplit, int M, int N, int K)
{
    static_assert(TM*TN == 256*RM*RN, "tile/micro mismatch");
    constexpr int PAD = 4;
    __shared__ float As[TK][TM+PAD];
    __shared__ float Ws[TK][TN+PAD];
    const int tid = threadIdx.x;
    const int m0 = blockIdx.x * TM;
    const int n0 = blockIdx.y * TN;
    constexpr int TNR = TN / RN;
    const int tm = tid / TNR;
    const int tn = tid % TNR;

    float acc[RM][RN];
#pragma unroll
    for (int i=0;i<RM;i++)
#pragma unroll
      for (int j=0;j<RN;j++) acc[i][j]=0.f;

    constexpr int K4 = TK/4;
    constexpr int AV = TM*K4/256;
    constexpr int WV = TN*K4/256;

    for (int k0=0;k0<K;k0+=TK){
#pragma unroll
        for (int p=0;p<AV;p++){
            const int f = tid + p*256;
            const int kf = f % K4, mm = f / K4;
            float4 v;
            if (APAIR){
                const unsigned short* Hg = (const unsigned short*)A;
                const unsigned short* Lg = (const unsigned short*)Alo;
                const size_t g = (size_t)(m0+mm)*K + k0 + kf*4;
                ushort4 hv = *reinterpret_cast<const ushort4*>(&Hg[g]);
                ushort4 lv = *reinterpret_cast<const ushort4*>(&Lg[g]);
                v.x = bf2f(hv.x)+bf2f(lv.x); v.y = bf2f(hv.y)+bf2f(lv.y);
                v.z = bf2f(hv.z)+bf2f(lv.z); v.w = bf2f(hv.w)+bf2f(lv.w);
            } else {
                v = *reinterpret_cast<const float4*>(A + (size_t)(m0+mm)*K + k0 + kf*4);
            }
            As[kf*4+0][mm]=v.x; As[kf*4+1][mm]=v.y; As[kf*4+2][mm]=v.z; As[kf*4+3][mm]=v.w;
        }
        if (BL==0){
#pragma unroll
            for (int p=0;p<WV;p++){
                const int f = tid + p*256;
                const int kf = f % K4, nn = f / K4;
                const int ng = n0 + nn;
                float4 v = make_float4(0.f,0.f,0.f,0.f);
                if (ng < N) v = *reinterpret_cast<const float4*>(W + (size_t)ng*K + k0 + kf*4);
                Ws[kf*4+0][nn]=v.x; Ws[kf*4+1][nn]=v.y; Ws[kf*4+2][nn]=v.z; Ws[kf*4+3][nn]=v.w;
            }
        } else {
            constexpr int NV4 = TN/4;
#pragma unroll
            for (int p=0;p<WV;p++){
                const int f = tid + p*256;
                const int nn4 = f % NV4, kk = f / NV4;
                float4 v = *reinterpret_cast<const float4*>(W + (size_t)(k0+kk)*N + n0 + nn4*4);
                *reinterpret_cast<float4*>(&Ws[kk][nn4*4]) = v;
            }
        }
        __syncthreads();
#pragma unroll
        for (int k=0;k<TK;k++){
            float a[RM], b[RN];
#pragma unroll
            for (int i=0;i<RM;i+=4){
                const float4 v = *reinterpret_cast<const float4*>(&As[k][tm*RM+i]);
                a[i]=v.x;a[i+1]=v.y;a[i+2]=v.z;a[i+3]=v.w;
            }
#pragma unroll
            for (int j=0;j<RN;j+=4){
                const float4 v = *reinterpret_cast<const float4*>(&Ws[k][tn*RN+j]);
                b[j]=v.x;b[j+1]=v.y;b[j+2]=v.z;b[j+3]=v.w;
            }
#pragma unroll
            for (int i=0;i<RM;i++)
#pragma unroll
                for (int j=0;j<RN;j++)
                    acc[i][j] = fmaf(a[i], b[j], acc[i][j]);
        }
        __syncthreads();
    }

    const int mb = m0 + tm*RM;
    const int nb = n0 + tn*RN;
#pragma unroll
    for (int i=0;i<RM;i++){
        const int m = mb + i;
        float s = 1.f;
        if (EPI==3){ if (scale4 && m < nsplit) s = scale4[m*4+3]; }
#pragma unroll
        for (int j=0;j<RN;j+=4){
            const int n = nb + j;
            if (n >= N) continue;
            float4 v = make_float4(acc[i][j],acc[i][j+1],acc[i][j+2],acc[i][j+3]);
            if (EPI==0){
                if (bias){ v.x+=bias[n]; v.y+=bias[n+1]; v.z+=bias[n+2]; v.w+=bias[n+3]; }
                *reinterpret_cast<float4*>(O0 + (size_t)m*N + n) = v;
            } else {
                unsigned short* Oh = (unsigned short*)O0;
                unsigned short* Ol = (unsigned short*)O1;
                unsigned short h0,h1,h2,h3,l0,l1,l2,l3;
                split2(v.x*s,h0,l0); split2(v.y*s,h1,l1);
                split2(v.z*s,h2,l2); split2(v.w*s,h3,l3);
                *reinterpret_cast<ushort4*>(&Oh[(size_t)m*N + n]) = make_ushort4(h0,h1,h2,h3);
                *reinterpret_cast<ushort4*>(&Ol[(size_t)m*N + n]) = make_ushort4(l0,l1,l2,l3);
            }
        }
    }
}

// ---------------------------------------------------------------------------
// bf16x3 MFMA GEMM. A: M x K as bf16 hi/lo planes. B: N x K as bf16 hi/lo.
// C = Ah*Bh + Al*Bh + Ah*Bl accumulated fp32 in 16x16x32 MFMA.
// LDS q-plane layout: plane[q][row][8] so frag ds_read_b128 is ~conflict-free.
// EPI 1 (xz): col<512: u=silu(v+bias) -> split -> Uh/Ul (stride 512);
//             col>=512: z=v+bias -> Zh fp16 (stride 512)
// EPI 2 (tail): col<64: tanh(v+e0[col]) -> O0; else clip(v+e1[col-64]) -> O1
// ---------------------------------------------------------------------------
template<int TM,int TN,int WM,int WN,int EPI>
__global__ __launch_bounds__(256) void mgemm(
    const unsigned short* __restrict__ Ah_g, const unsigned short* __restrict__ Al_g,
    const unsigned short* __restrict__ Bh_g, const unsigned short* __restrict__ Bl_g,
    const float* __restrict__ bias,
    const float* __restrict__ e0, const float* __restrict__ e1,
    unsigned short* __restrict__ Uh, unsigned short* __restrict__ Ul,
    __half* __restrict__ Zh,
    float* __restrict__ O0, float* __restrict__ O1,
    int K)
{
    constexpr int WAVES_N = TN/WN;
    constexpr int WAVES_M = TM/WM;
    static_assert(WAVES_M*WAVES_N == 4, "4 waves");
    constexpr int MT = WM/16, NT = WN/16;
    constexpr int ASZ = 4*TM*8;   // shorts per A plane (4 q-planes)
    constexpr int BSZ = 4*TN*8;
    __shared__ unsigned short sm[2*ASZ + 2*BSZ];

    const int tid = threadIdx.x;
    const int m0 = blockIdx.x * TM;
    const int n0 = blockIdx.y * TN;
    const int lane = tid & 63, wid = tid >> 6;
    const int quad = lane >> 4, l16 = lane & 15;
    const int wm = (wid / WAVES_N) * WM;
    const int wn = (wid % WAVES_N) * WN;

    f32x4 acc[MT][NT];
#pragma unroll
    for (int i=0;i<MT;i++)
#pragma unroll
      for (int j=0;j<NT;j++) acc[i][j] = (f32x4){0.f,0.f,0.f,0.f};

    constexpr int IA = TM/64;   // 16B-per-lane passes per A plane
    constexpr int IB = TN/64;

    for (int k0=0; k0<K; k0+=32){
#pragma unroll
        for (int it=0; it<IA; ++it){
            const int f = it*256 + tid;
            const int m = f >> 2, r = f & 3;
            const size_t g = (size_t)(m0+m)*K + k0 + r*8;
            *reinterpret_cast<uint4*>(&sm[      r*TM*8 + m*8]) = *reinterpret_cast<const uint4*>(&Ah_g[g]);
            *reinterpret_cast<uint4*>(&sm[ASZ + r*TM*8 + m*8]) = *reinterpret_cast<const uint4*>(&Al_g[g]);
        }
#pragma unroll
        for (int it=0; it<IB; ++it){
            const int f = it*256 + tid;
            const int n = f >> 2, r = f & 3;
            const size_t g = (size_t)(n0+n)*K + k0 + r*8;
            *reinterpret_cast<uint4*>(&sm[2*ASZ       + r*TN*8 + n*8]) = *reinterpret_cast<const uint4*>(&Bh_g[g]);
            *reinterpret_cast<uint4*>(&sm[2*ASZ + BSZ + r*TN*8 + n*8]) = *reinterpret_cast<const uint4*>(&Bl_g[g]);
        }
        __syncthreads();

        bf16x8 ah[MT], al[MT], bh[NT], bl[NT];
#pragma unroll
        for (int mt=0; mt<MT; ++mt){
            const int off = quad*TM*8 + (wm + mt*16 + l16)*8;
            ah[mt] = *reinterpret_cast<const bf16x8*>(&sm[off]);
            al[mt] = *reinterpret_cast<const bf16x8*>(&sm[ASZ + off]);
        }
#pragma unroll
        for (int nt=0; nt<NT; ++nt){
            const int off = quad*TN*8 + (wn + nt*16 + l16)*8;
            bh[nt] = *reinterpret_cast<const bf16x8*>(&sm[2*ASZ + off]);
            bl[nt] = *reinterpret_cast<const bf16x8*>(&sm[2*ASZ + BSZ + off]);
        }
#pragma unroll
        for (int mt=0; mt<MT; ++mt)
#pragma unroll
        for (int nt=0; nt<NT; ++nt){
            acc[mt][nt] = __builtin_amdgcn_mfma_f32_16x16x32_bf16(ah[mt], bh[nt], acc[mt][nt], 0,0,0);
            acc[mt][nt] = __builtin_amdgcn_mfma_f32_16x16x32_bf16(al[mt], bh[nt], acc[mt][nt], 0,0,0);
            acc[mt][nt] = __builtin_amdgcn_mfma_f32_16x16x32_bf16(ah[mt], bl[nt], acc[mt][nt], 0,0,0);
        }
        __syncthreads();
    }

    // epilogue: C/D layout col=lane&15, row=quad*4+reg  [m89 verified]
#pragma unroll
    for (int mt=0; mt<MT; ++mt)
#pragma unroll
    for (int nt=0; nt<NT; ++nt)
#pragma unroll
    for (int r=0; r<4; ++r){
        const int row = m0 + wm + mt*16 + quad*4 + r;
        const int col = n0 + wn + nt*16 + l16;
        float v = acc[mt][nt][r];
        if (EPI==1){
            v += bias[col];
            if (col < 512){
                const float us = v / (1.f + expf(-v));
                unsigned short h,l; split2(us,h,l);
                const size_t off = (size_t)row*512 + col;
                Uh[off]=h; Ul[off]=l;
            } else {
                Zh[(size_t)row*512 + (col-512)] = __float2half(v);
            }
        } else {
            if (col < 64){
                O0[(size_t)row*64 + col] = tanhf(v + e0[col]);
            } else {
                O1[(size_t)row*64 + (col-64)] = fminf(fmaxf(v + e1[col-64], -5.f), 2.f);
            }
        }
    }
}

// split perception into bf16 hi/lo planes (4 elems/thread)
__global__ __launch_bounds__(256) void split_pair(
    const float* __restrict__ X, unsigned short* __restrict__ H, unsigned short* __restrict__ L)
{
    const size_t i = (size_t)blockIdx.x*256 + threadIdx.x;
    float4 v = *reinterpret_cast<const float4*>(&X[i*4]);
    unsigned short h0,h1,h2,h3,l0,l1,l2,l3;
    split2(v.x,h0,l0); split2(v.y,h1,l1); split2(v.z,h2,l2); split2(v.w,h3,l3);
    *reinterpret_cast<ushort4*>(&H[i*4]) = make_ushort4(h0,h1,h2,h3);
    *reinterpret_cast<ushort4*>(&L[i*4]) = make_ushort4(l0,l1,l2,l3);
}

// b1[n] = (in_proj[n,:] . b_in) (*conv3 + conv_b for n<512)
__global__ void prep_bias(const float* __restrict__ in_proj, const float* __restrict__ b_in,
                          const float* __restrict__ conv_w, const float* __restrict__ conv_b,
                          float* __restrict__ b1)
{
    const int n = blockIdx.x*256 + threadIdx.x;
    float acc = 0.f;
    for (int j=0;j<256;j++) acc = fmaf(in_proj[n*256+j], b_in[j], acc);
    b1[n] = (n < 512) ? fmaf(acc, conv_w[n*4+3], conv_b[n]) : acc;
}

// y = u*(softplus(dt.dtw+dtb)*(B.C)+Dskip)*silu(z); write y as bf16 pair in-place
__global__ __launch_bounds__(256) void ssm_ew(
    const float* __restrict__ xdbl, const float* __restrict__ dtw,
    const float* __restrict__ dtb, const float* __restrict__ dskip,
    const __half* __restrict__ Zh,
    unsigned short* __restrict__ Uh, unsigned short* __restrict__ Ul)
{
    __shared__ float sxd[48];
    const int b = blockIdx.x;
    const int tid = threadIdx.x;
    const int d = blockIdx.y*256 + tid;
    if (tid < 48) sxd[tid] = xdbl[(size_t)b*48 + tid];
    __syncthreads();
    float BC = 0.f;
#pragma unroll
    for (int n=0;n<16;n++) BC = fmaf(sxd[16+n], sxd[32+n], BC);
    float dtv = dtb[d];
#pragma unroll
    for (int r=0;r<16;r++) dtv = fmaf(sxd[r], dtw[d*16+r], dtv);
    const float delta = (dtv > 20.f) ? dtv : log1pf(expf(dtv));
    const size_t off = (size_t)b*512 + d;
    const float u = bf2f(Uh[off]) + bf2f(Ul[off]);
    const float z = __half2float(Zh[off]);
    float y = u * fmaf(delta, BC, dskip[d]);
    y *= z / (1.f + expf(-z));
    unsigned short h,l; split2(y,h,l);
    Uh[off]=h; Ul[off]=l;
}

extern "C" void kernel_launch(void* const* d_in, const int* in_sizes, int n_in,
                              void* d_out, int out_size, void* d_ws, size_t ws_size,
                              hipStream_t stream) {
    (void)in_sizes; (void)n_in; (void)out_size; (void)ws_size;
    const float* percep  = (const float*)d_in[0];   // (8192,512)
    const float* W_in    = (const float*)d_in[1];   // (256,512)
    const float* b_in    = (const float*)d_in[2];   // (256)
    const float* mu_w    = (const float*)d_in[3];   // (64,256)
    const float* mu_b    = (const float*)d_in[4];   // (64)
    const float* ls_w    = (const float*)d_in[5];   // (64,256)
    const float* ls_b    = (const float*)d_in[6];   // (64)
    const float* in_proj = (const float*)d_in[7];   // (1024,256)
    const float* conv_w  = (const float*)d_in[8];   // (512,4)
    const float* conv_b  = (const float*)d_in[9];   // (512)
    const float* x_proj  = (const float*)d_in[10];  // (48,512)
    const float* dt_w    = (const float*)d_in[11];  // (512,16)
    const float* dt_b    = (const float*)d_in[12];  // (512)
    // d_in[13] A_log unused at L=1 (h0=0)
    const float* Dskip   = (const float*)d_in[14];  // (512)
    const float* out_proj= (const float*)d_in[15];  // (256,512)

    // workspace layout (42.3 MB)
    unsigned short* W1h = (unsigned short*)d_ws;          // 1024*512
    unsigned short* W1l = W1h + 524288;
    unsigned short* Wth = W1l + 524288;                   // 128*512
    unsigned short* Wtl = Wth + 65536;
    float* b1 = (float*)(Wtl + 65536);                    // 1024
    unsigned short* Uh = (unsigned short*)(b1 + 1024);    // 8192*512
    unsigned short* Ul = Uh + 4194304;
    __half* Zh = (__half*)(Ul + 4194304);                 // 8192*512 fp16
    unsigned short* Ph = (unsigned short*)(Zh + 4194304); // 8192*512 (dead after K1)
    unsigned short* Pl = Ph + 4194304;
    float* xdbl = (float*)Ph;                             // alias (born after P dies)

    float* mu_o = (float*)d_out;
    float* ls_o = (float*)d_out + (size_t)BATCH*64;

    dim3 blk(256);
    // P0: split perception -> bf16 hi/lo
    split_pair<<<dim3(BATCH*512/1024), blk, 0, stream>>>(percep, Ph, Pl);
    // prep: Wf = in_proj @ W_in, u-rows scaled by conv_w[:,3], split -> W1h/W1l
    gemm_k<64,64,16,4,4,3,1,0><<<dim3(16,8), blk, 0, stream>>>(
        in_proj, nullptr, W_in, nullptr, conv_w, (float*)W1h, (float*)W1l, 512, 1024, 512, 256);
    // prep: Wt = [mu_w; ls_w] @ out_proj, split -> Wth/Wtl
    gemm_k<64,64,16,4,4,3,1,0><<<dim3(1,8), blk, 0, stream>>>(
        mu_w, nullptr, out_proj, nullptr, nullptr, (float*)Wth, (float*)Wtl, 0, 64, 512, 256);
    gemm_k<64,64,16,4,4,3,1,0><<<dim3(1,8), blk, 0, stream>>>(
        ls_w, nullptr, out_proj, nullptr, nullptr, (float*)(Wth + 64*512), (float*)(Wtl + 64*512), 0, 64, 512, 256);
    // prep: fused bias b1 = in_proj@b_in (conv-folded)
    prep_bias<<<dim3(4), blk, 0, stream>>>(in_proj, b_in, conv_w, conv_b, b1);
    // K1: xz = p @ Wf.T + b1 ; u=silu -> Uh/Ul ; z -> Zh     (M=8192,N=1024,K=512)
    mgemm<128,128,64,64,1><<<dim3(64,8), blk, 0, stream>>>(
        Ph, Pl, W1h, W1l, b1, nullptr, nullptr, Uh, Ul, Zh, nullptr, nullptr, 512);
    // K2: x_dbl = u @ x_proj.T   (fp32 vector, N=48)
    gemm_k<64,64,16,4,4,0,0,1><<<dim3(128,1), blk, 0, stream>>>(
        (const float*)Uh, (const float*)Ul, x_proj, nullptr, nullptr, xdbl, nullptr, 0, BATCH, 48, 512);
    // K3: ssm elementwise -> y (bf16 pair, in place over U)
    ssm_ew<<<dim3(BATCH,2), blk, 0, stream>>>(xdbl, dt_w, dt_b, Dskip, Zh, Uh, Ul);
    // K4: [mu|ls] = act(y @ Wt.T + b)   (M=8192,N=128,K=512)
    mgemm<64,128,32,64,2><<<dim3(128,1), blk, 0, stream>>>(
        Uh, Ul, Wth, Wtl, nullptr, mu_b, ls_b, nullptr, nullptr, nullptr, mu_o, ls_o, 512);
}

// Round 3
// 219.352 us; speedup vs baseline: 1.5733x; 1.2339x over previous
//
#include <hip/hip_runtime.h>
#include <hip/hip_fp16.h>
#include <cmath>

#define BATCH 8192

typedef short bf16x8 __attribute__((ext_vector_type(8)));
typedef float f32x4 __attribute__((ext_vector_type(4)));

__device__ __forceinline__ float bf2f(unsigned short s){
    return __uint_as_float(((unsigned)s) << 16);
}
__device__ __forceinline__ void split2(float x, unsigned short& h, unsigned short& l){
    unsigned u = __float_as_uint(x);
    unsigned hr = u + 0x7fffu + ((u >> 16) & 1u);
    unsigned short hs = (unsigned short)(hr >> 16);
    float hf = __uint_as_float(((unsigned)hs) << 16);
    float d = x - hf;
    unsigned v = __float_as_uint(d);
    unsigned short ls = (unsigned short)((v + 0x7fffu + ((v >> 16) & 1u)) >> 16);
    h = hs; l = ls;
}
__device__ __forceinline__ float fsig(float x){ return 1.f / (1.f + __expf(-x)); }
__device__ __forceinline__ float ftanh(float x){
    x = fminf(fmaxf(x, -10.f), 10.f);
    const float e = __expf(2.f*x);
    return (e - 1.f) / (e + 1.f);
}

// ---------------------------------------------------------------------------
// split perception into bf16 hi/lo planes (4 elems/thread)
// ---------------------------------------------------------------------------
__global__ __launch_bounds__(256) void split_pair(
    const float* __restrict__ X, unsigned short* __restrict__ H, unsigned short* __restrict__ L)
{
    const size_t i = (size_t)blockIdx.x*256 + threadIdx.x;
    float4 v = *reinterpret_cast<const float4*>(&X[i*4]);
    unsigned short h0,h1,h2,h3,l0,l1,l2,l3;
    split2(v.x,h0,l0); split2(v.y,h1,l1); split2(v.z,h2,l2); split2(v.w,h3,l3);
    *reinterpret_cast<ushort4*>(&H[i*4]) = make_ushort4(h0,h1,h2,h3);
    *reinterpret_cast<ushort4*>(&L[i*4]) = make_ushort4(l0,l1,l2,l3);
}

// ---------------------------------------------------------------------------
// One launch: all weight preprocessing.
//  bx 0..15 : Wf = in_proj @ W_in   (1024x512, K=256), rows<512 scaled conv3
//  bx 16/17 : Wt = [mu_w;ls_w] @ out_proj (128x512, K=256)
//  bx 18    : b1[n] = (in_proj[n,:].b_in) (*conv3+conv_b for n<512)
//  outputs split to bf16 hi/lo planes
// ---------------------------------------------------------------------------
__global__ __launch_bounds__(256) void prep_all(
    const float* __restrict__ in_proj, const float* __restrict__ W_in,
    const float* __restrict__ b_in,
    const float* __restrict__ mu_w, const float* __restrict__ ls_w,
    const float* __restrict__ conv_w, const float* __restrict__ conv_b,
    const float* __restrict__ out_proj,
    unsigned short* __restrict__ W1h, unsigned short* __restrict__ W1l,
    unsigned short* __restrict__ Wth, unsigned short* __restrict__ Wtl,
    float* __restrict__ b1)
{
    const int bx = blockIdx.x, by = blockIdx.y;
    const int tid = threadIdx.x;
    if (bx == 18){
        if (by) return;
        for (int p=0;p<4;p++){
            const int n = tid + p*256;
            float acc = 0.f;
            for (int j=0;j<256;j++) acc = fmaf(in_proj[n*256+j], b_in[j], acc);
            b1[n] = (n < 512) ? fmaf(acc, conv_w[n*4+3], conv_b[n]) : acc;
        }
        return;
    }
    const float* A; unsigned short *Oh, *Ol; int m0; bool doscale;
    const float* B;
    if (bx < 16){ A = in_proj + (size_t)bx*64*256; B = W_in; Oh=W1h; Ol=W1l; m0=bx*64; doscale=true; }
    else { A = (bx==16 ? mu_w : ls_w); B = out_proj; Oh=Wth; Ol=Wtl; m0=(bx-16)*64; doscale=false; }
    const int n0 = by*64;

    __shared__ float As[16][68];
    __shared__ float Ws[16][68];
    const int tm = tid/16, tn = tid%16;
    float acc[4][4];
#pragma unroll
    for (int i=0;i<4;i++)
#pragma unroll
      for (int j=0;j<4;j++) acc[i][j]=0.f;

    for (int k0=0;k0<256;k0+=16){
        { // A: 64 rows x 4 float4
            const int kf = tid & 3, mm = tid >> 2;
            float4 v = *reinterpret_cast<const float4*>(A + (size_t)mm*256 + k0 + kf*4);
            As[kf*4+0][mm]=v.x; As[kf*4+1][mm]=v.y; As[kf*4+2][mm]=v.z; As[kf*4+3][mm]=v.w;
        }
        { // B (K x 512): 16 k x 16 float4
            const int nn4 = tid & 15, kk = tid >> 4;
            float4 v = *reinterpret_cast<const float4*>(B + (size_t)(k0+kk)*512 + n0 + nn4*4);
            *reinterpret_cast<float4*>(&Ws[kk][nn4*4]) = v;
        }
        __syncthreads();
#pragma unroll
        for (int k=0;k<16;k++){
            float a[4], b[4];
            const float4 av = *reinterpret_cast<const float4*>(&As[k][tm*4]);
            a[0]=av.x;a[1]=av.y;a[2]=av.z;a[3]=av.w;
            const float4 bv = *reinterpret_cast<const float4*>(&Ws[k][tn*4]);
            b[0]=bv.x;b[1]=bv.y;b[2]=bv.z;b[3]=bv.w;
#pragma unroll
            for (int i=0;i<4;i++)
#pragma unroll
                for (int j=0;j<4;j++) acc[i][j] = fmaf(a[i], b[j], acc[i][j]);
        }
        __syncthreads();
    }
#pragma unroll
    for (int i=0;i<4;i++){
        const int gm = m0 + tm*4 + i;
        const float s = (doscale && gm < 512) ? conv_w[gm*4+3] : 1.f;
        const int n = n0 + tn*4;
        unsigned short h[4], l[4];
#pragma unroll
        for (int j=0;j<4;j++) split2(acc[i][j]*s, h[j], l[j]);
        *reinterpret_cast<ushort4*>(&Oh[(size_t)gm*512 + n]) = make_ushort4(h[0],h[1],h[2],h[3]);
        *reinterpret_cast<ushort4*>(&Ol[(size_t)gm*512 + n]) = make_ushort4(l[0],l[1],l[2],l[3]);
    }
}

// ---------------------------------------------------------------------------
// bf16x3 MFMA GEMM (16x16x32), A/B as bf16 hi/lo planes.
// EPI 1: col<512: Uf[row*512+col] = silu(v+b1) fp32 ; col>=512: Zh = fp16(v+b1)
// EPI 2: col<64: O0 = tanh(v+e0[col]) ; else O1 = clip(v+e1[col-64],-5,2)
// ---------------------------------------------------------------------------
template<int TM,int TN,int WM,int WN,int EPI>
__global__ __launch_bounds__(256) void mgemm(
    const unsigned short* __restrict__ Ah_g, const unsigned short* __restrict__ Al_g,
    const unsigned short* __restrict__ Bh_g, const unsigned short* __restrict__ Bl_g,
    const float* __restrict__ bias,
    const float* __restrict__ e0, const float* __restrict__ e1,
    float* __restrict__ Uf, __half* __restrict__ Zh,
    float* __restrict__ O0, float* __restrict__ O1,
    int K)
{
    constexpr int WAVES_N = TN/WN;
    constexpr int MT = WM/16, NT = WN/16;
    constexpr int ASZ = 4*TM*8;
    constexpr int BSZ = 4*TN*8;
    __shared__ unsigned short sm[2*ASZ + 2*BSZ];

    const int tid = threadIdx.x;
    const int m0 = blockIdx.x * TM;
    const int n0 = blockIdx.y * TN;
    const int lane = tid & 63, wid = tid >> 6;
    const int quad = lane >> 4, l16 = lane & 15;
    const int wm = (wid / WAVES_N) * WM;
    const int wn = (wid % WAVES_N) * WN;

    f32x4 acc[MT][NT];
#pragma unroll
    for (int i=0;i<MT;i++)
#pragma unroll
      for (int j=0;j<NT;j++) acc[i][j] = (f32x4){0.f,0.f,0.f,0.f};

    constexpr int IA = TM/64;
    constexpr int IB = TN/64;

    for (int k0=0; k0<K; k0+=32){
#pragma unroll
        for (int it=0; it<IA; ++it){
            const int f = it*256 + tid;
            const int m = f >> 2, r = f & 3;
            const size_t g = (size_t)(m0+m)*K + k0 + r*8;
            *reinterpret_cast<uint4*>(&sm[      r*TM*8 + m*8]) = *reinterpret_cast<const uint4*>(&Ah_g[g]);
            *reinterpret_cast<uint4*>(&sm[ASZ + r*TM*8 + m*8]) = *reinterpret_cast<const uint4*>(&Al_g[g]);
        }
#pragma unroll
        for (int it=0; it<IB; ++it){
            const int f = it*256 + tid;
            const int n = f >> 2, r = f & 3;
            const size_t g = (size_t)(n0+n)*K + k0 + r*8;
            *reinterpret_cast<uint4*>(&sm[2*ASZ       + r*TN*8 + n*8]) = *reinterpret_cast<const uint4*>(&Bh_g[g]);
            *reinterpret_cast<uint4*>(&sm[2*ASZ + BSZ + r*TN*8 + n*8]) = *reinterpret_cast<const uint4*>(&Bl_g[g]);
        }
        __syncthreads();

        bf16x8 ah[MT], al[MT], bh[NT], bl[NT];
#pragma unroll
        for (int mt=0; mt<MT; ++mt){
            const int off = quad*TM*8 + (wm + mt*16 + l16)*8;
            ah[mt] = *reinterpret_cast<const bf16x8*>(&sm[off]);
            al[mt] = *reinterpret_cast<const bf16x8*>(&sm[ASZ + off]);
        }
#pragma unroll
        for (int nt=0; nt<NT; ++nt){
            const int off = quad*TN*8 + (wn + nt*16 + l16)*8;
            bh[nt] = *reinterpret_cast<const bf16x8*>(&sm[2*ASZ + off]);
            bl[nt] = *reinterpret_cast<const bf16x8*>(&sm[2*ASZ + BSZ + off]);
        }
#pragma unroll
        for (int mt=0; mt<MT; ++mt)
#pragma unroll
        for (int nt=0; nt<NT; ++nt){
            acc[mt][nt] = __builtin_amdgcn_mfma_f32_16x16x32_bf16(ah[mt], bh[nt], acc[mt][nt], 0,0,0);
            acc[mt][nt] = __builtin_amdgcn_mfma_f32_16x16x32_bf16(al[mt], bh[nt], acc[mt][nt], 0,0,0);
            acc[mt][nt] = __builtin_amdgcn_mfma_f32_16x16x32_bf16(ah[mt], bl[nt], acc[mt][nt], 0,0,0);
        }
        __syncthreads();
    }

    // C/D layout: col=lane&15, row=quad*4+reg  [m89]
#pragma unroll
    for (int mt=0; mt<MT; ++mt)
#pragma unroll
    for (int nt=0; nt<NT; ++nt)
#pragma unroll
    for (int r=0; r<4; ++r){
        const int row = m0 + wm + mt*16 + quad*4 + r;
        const int col = n0 + wn + nt*16 + l16;
        float v = acc[mt][nt][r];
        if (EPI==1){
            v += bias[col];
            if (col < 512){
                Uf[(size_t)row*512 + col] = v * fsig(v);
            } else {
                Zh[(size_t)row*512 + (col-512)] = __float2half(v);
            }
        } else {
            if (col < 64){
                O0[(size_t)row*64 + col] = ftanh(v + e0[col]);
            } else {
                O1[(size_t)row*64 + (col-64)] = fminf(fmaxf(v + e1[col-64], -5.f), 2.f);
            }
        }
    }
}

// ---------------------------------------------------------------------------
// Fused: xdbl = u @ x_proj.T (N=48) then SSM elementwise, per 32-row block.
// y = u*(softplus(dt.dtw_d+dtb_d)*(B.C)+Dskip_d)*silu(z) -> bf16 pair Yh/Yl
// ---------------------------------------------------------------------------
__global__ __launch_bounds__(256) void xdbl_ssm(
    const float* __restrict__ Uf,      // (B,512) fp32
    const __half* __restrict__ Zh,     // (B,512) fp16
    const float* __restrict__ x_proj,  // (48,512)
    const float* __restrict__ dtw,     // (512,16)
    const float* __restrict__ dtb,     // (512)
    const float* __restrict__ dskip,   // (512)
    unsigned short* __restrict__ Yh, unsigned short* __restrict__ Yl)
{
    constexpr int TM=32, TK=32;
    __shared__ float As[TK][TM+2];
    __shared__ float Ws[TK][68];
    __shared__ float sdtw[512*17];
    __shared__ float sdtb[512], sdsk[512];
    __shared__ float sxd[TM][49];
    __shared__ float sBC[TM];

    const int tid = threadIdx.x;
    const int m0 = blockIdx.x * TM;

    // stage dt tables (conflict-free pad 17)
#pragma unroll
    for (int p=0;p<8;p++){
        const int f = p*256 + tid;           // [0,2048)
        const int d = f >> 2, j4 = (f & 3) * 4;
        const float4 v = *reinterpret_cast<const float4*>(&dtw[d*16 + j4]);
        float* dst = &sdtw[d*17 + j4];
        dst[0]=v.x; dst[1]=v.y; dst[2]=v.z; dst[3]=v.w;
    }
#pragma unroll
    for (int p=0;p<2;p++){
        const int d = p*256 + tid;
        sdtb[d] = dtb[d]; sdsk[d] = dskip[d];
    }

    // GEMM: xdbl(32x48) = Uf(32x512) @ x_proj.T
    const int tm = tid/16, tn = tid%16;   // rows tm*2+i, cols tn*4+j (64 guarded to 48)
    float acc[2][4];
#pragma unroll
    for (int i=0;i<2;i++)
#pragma unroll
      for (int j=0;j<4;j++) acc[i][j]=0.f;

    for (int k0=0;k0<512;k0+=TK){
        { // A: 32 rows x 8 float4 = 256
            const int kf = tid & 7, mm = tid >> 3;
            const float4 v = *reinterpret_cast<const float4*>(Uf + (size_t)(m0+mm)*512 + k0 + kf*4);
            As[kf*4+0][mm]=v.x; As[kf*4+1][mm]=v.y; As[kf*4+2][mm]=v.z; As[kf*4+3][mm]=v.w;
        }
#pragma unroll
        for (int p=0;p<2;p++){ // W: 48 rows x 8 float4 = 384
            const int f = p*256 + tid;
            if (f < 384){
                const int kf = f & 7, nn = f >> 3;
                const float4 v = *reinterpret_cast<const float4*>(x_proj + (size_t)nn*512 + k0 + kf*4);
                Ws[kf*4+0][nn]=v.x; Ws[kf*4+1][nn]=v.y; Ws[kf*4+2][nn]=v.z; Ws[kf*4+3][nn]=v.w;
            }
        }
        __syncthreads();
#pragma unroll
        for (int k=0;k<TK;k++){
            const float a0 = As[k][tm*2+0], a1 = As[k][tm*2+1];
            const float4 bv = *reinterpret_cast<const float4*>(&Ws[k][tn*4]);
            acc[0][0]=fmaf(a0,bv.x,acc[0][0]); acc[0][1]=fmaf(a0,bv.y,acc[0][1]);
            acc[0][2]=fmaf(a0,bv.z,acc[0][2]); acc[0][3]=fmaf(a0,bv.w,acc[0][3]);
            acc[1][0]=fmaf(a1,bv.x,acc[1][0]); acc[1][1]=fmaf(a1,bv.y,acc[1][1]);
            acc[1][2]=fmaf(a1,bv.z,acc[1][2]); acc[1][3]=fmaf(a1,bv.w,acc[1][3]);
        }
        __syncthreads();
    }
#pragma unroll
    for (int i=0;i<2;i++)
#pragma unroll
    for (int j=0;j<4;j++){
        const int c = tn*4+j;
        if (c < 48) sxd[tm*2+i][c] = acc[i][j];
    }
    __syncthreads();
    if (tid < TM){
        float bc = 0.f;
#pragma unroll
        for (int n=0;n<16;n++) bc = fmaf(sxd[tid][16+n], sxd[tid][32+n], bc);
        sBC[tid] = bc;
    }
    __syncthreads();

    // elementwise: 32 rows x 512 d = 16384 / 256 threads = 64 each
#pragma unroll 4
    for (int i=0;i<64;i++){
        const int idx = i*256 + tid;
        const int r = idx >> 9, d = idx & 511;
        float dtv = sdtb[d];
#pragma unroll
        for (int j=0;j<16;j++) dtv = fmaf(sxd[r][j], sdtw[d*17+j], dtv);
        const float delta = (dtv > 20.f) ? dtv : __logf(1.f + __expf(dtv));
        const size_t off = (size_t)(m0+r)*512 + d;
        const float u = Uf[off];
        const float z = __half2float(Zh[off]);
        float y = u * fmaf(delta, sBC[r], sdsk[d]);
        y *= z * fsig(z);
        unsigned short h,l; split2(y,h,l);
        Yh[off]=h; Yl[off]=l;
    }
}

extern "C" void kernel_launch(void* const* d_in, const int* in_sizes, int n_in,
                              void* d_out, int out_size, void* d_ws, size_t ws_size,
                              hipStream_t stream) {
    (void)in_sizes; (void)n_in; (void)out_size; (void)ws_size;
    const float* percep  = (const float*)d_in[0];
    const float* W_in    = (const float*)d_in[1];
    const float* b_in    = (const float*)d_in[2];
    const float* mu_w    = (const float*)d_in[3];
    const float* mu_b    = (const float*)d_in[4];
    const float* ls_w    = (const float*)d_in[5];
    const float* ls_b    = (const float*)d_in[6];
    const float* in_proj = (const float*)d_in[7];
    const float* conv_w  = (const float*)d_in[8];
    const float* conv_b  = (const float*)d_in[9];
    const float* x_proj  = (const float*)d_in[10];
    const float* dt_w    = (const float*)d_in[11];
    const float* dt_b    = (const float*)d_in[12];
    // d_in[13] A_log unused at L=1 (h0=0)
    const float* Dskip   = (const float*)d_in[14];
    const float* out_proj= (const float*)d_in[15];

    char* ws = (char*)d_ws;
    unsigned short* W1h = (unsigned short*)(ws);            // 1 MB
    unsigned short* W1l = (unsigned short*)(ws + (1u<<20));
    unsigned short* Wth = (unsigned short*)(ws + (2u<<20)); // 128 KB
    unsigned short* Wtl = (unsigned short*)(ws + (2u<<20) + (128u<<10));
    float*          b1  = (float*)         (ws + (2u<<20) + (256u<<10)); // 4 KB
    float*          Uf  = (float*)         (ws + (4u<<20));  // 16 MB
    __half*         Zh  = (__half*)        (ws + (20u<<20)); // 8 MB
    unsigned short* Yh  = (unsigned short*)(ws + (28u<<20)); // 8 MB
    unsigned short* Yl  = (unsigned short*)(ws + (36u<<20)); // 8 MB
    unsigned short* Ph  = (unsigned short*)(ws + (44u<<20)); // 8 MB
    unsigned short* Pl  = (unsigned short*)(ws + (52u<<20)); // 8 MB

    float* mu_o = (float*)d_out;
    float* ls_o = (float*)d_out + (size_t)BATCH*64;

    dim3 blk(256);
    split_pair<<<dim3(BATCH*512/1024), blk, 0, stream>>>(percep, Ph, Pl);
    prep_all<<<dim3(19,8), blk, 0, stream>>>(
        in_proj, W_in, b_in, mu_w, ls_w, conv_w, conv_b, out_proj,
        W1h, W1l, Wth, Wtl, b1);
    // K1: xz = p @ Wf.T + b1 ; u=silu -> Uf fp32 ; z -> Zh fp16
    mgemm<128,128,64,64,1><<<dim3(64,8), blk, 0, stream>>>(
        Ph, Pl, W1h, W1l, b1, nullptr, nullptr, Uf, Zh, nullptr, nullptr, 512);
    // K23: xdbl + ssm -> Y pair
    xdbl_ssm<<<dim3(BATCH/32), blk, 0, stream>>>(
        Uf, Zh, x_proj, dt_w, dt_b, Dskip, Yh, Yl);
    // K4: [mu|ls] = act(y @ Wt.T + b)
    mgemm<64,64,32,32,2><<<dim3(128,2), blk, 0, stream>>>(
        Yh, Yl, Wth, Wtl, nullptr, mu_b, ls_b, nullptr, nullptr, mu_o, ls_o, 512);
}